// Round 26
// baseline (43.086 us; speedup 1.0000x reference)
//
#include <hip/hip_runtime.h>
#include <hip/hip_fp16.h>
#include <cstddef>

#define DIM 2048
#define NTOK 8192
#define NEUMANN_ITERS 6

// Math (validated rounds 1-25):
//   omega = P Q^T, P=[U|V], Q=[sV|-sU], G = Q^T P  (16x16)
//   Y = (I - G/2)^{-1}(I + G/2)  via Neumann-Horner: Y <- B + 0.5*G*Y, B=I+G/2
//   out = x + c . W^T,  c[r][k] = 0.5*s* sum_j Z[k][j] b[r][j],  Z = I + Y,
//     b[j<8] = av[j], b[j>=8] = -au[j-8];  a = [x.U | x.V] = x.W
//   G[r][c] = r<8 ? +s*WtW[8+r][c] : -s*WtW[r-8][c]  (in-kernel gram, r24)
//
// r26 change (on r25 champion, 41.5us): NO LDS W. U,V (256KB) are
// L2-resident and shared by all blocks; gather B-fragments from global:
//   phase1/gram: W[d0..d0+3][rA] = 4 scalar f32 (stride 32B) + 2 pkh
//   phase2:      W[dcol0+rA][g*4..+3] = ONE float4 (U4/V4) + 2 pkh
// LDS 75KB -> 9.5KB => occupancy VGPR-bound: ~5 blocks/CU = 20 waves/CU
// of INDEPENDENT work (r23 proved intra-block waves don't help — barrier
// coupled; cross-block waves are free). Fragment contracts byte-identical
// to r25 (A row=l&15, B col=l&15, k=(l>>4)*4+j; swapped-D epilogue).

typedef _Float16 h4 __attribute__((ext_vector_type(4)));
typedef float f32x4 __attribute__((ext_vector_type(4)));

__device__ __forceinline__ unsigned pkh(float lo, float hi) {
  auto p = __builtin_amdgcn_cvt_pkrtz(lo, hi);   // v_cvt_pkrtz_f16_f32
  return __builtin_bit_cast(unsigned, p);
}

// ---------------------------------------------------------------------------
// Fused MFMA kernel, zero staged W. 256 thr = 4 waves; 16 rows/block;
// grid 512. No workspace.
// ---------------------------------------------------------------------------
__global__ __launch_bounds__(256) void rora_fused(
    const float* __restrict__ x, const float* __restrict__ U,
    const float* __restrict__ V, const float* __restrict__ gate,
    float* __restrict__ out) {
  __shared__ float Gs[16][17];        // 1,088 B
  __shared__ float Ya[16][17];        // 1,088 B
  __shared__ float Yb[16][17];        // 1,088 B
  __shared__ float Wtw[16][17];       // 1,088 B
  __shared__ float As[16][17];        // 1,088 B
  __shared__ float Ared[4][64][4];    // 4,096 B   (total ~9.5 KB)
  const int t = threadIdx.x;
  const int lane = t & 63, wv = t >> 6;
  const int rA = lane & 15, g = lane >> 4;

  // W-column gather source for this thread's B-fragment column (k = rA)
  const float* Wcol = ((rA < 8) ? U : V) + (rA & 7);   // W[d][rA] = Wcol[8*d]

  // ---- gram: WtW = W^T W via MFMA; wave wv covers K [wv*512,+512) ----
  {
    f32x4 acc = {0.f, 0.f, 0.f, 0.f};
#pragma unroll 4
    for (int step = 0; step < 32; ++step) {
      const int d0 = wv * 512 + step * 16 + g * 4;
      const float w0 = Wcol[8 * (d0 + 0)], w1 = Wcol[8 * (d0 + 1)];
      const float w2 = Wcol[8 * (d0 + 2)], w3 = Wcol[8 * (d0 + 3)];
      uint2 wu = {pkh(w0, w1), pkh(w2, w3)};
      const h4 wf = __builtin_bit_cast(h4, wu);   // W[d0..d0+3][rA]
      acc = __builtin_amdgcn_mfma_f32_16x16x16f16(wf, wf, acc, 0, 0, 0);
    }
    Ared[wv][lane][0] = acc[0];
    Ared[wv][lane][1] = acc[1];
    Ared[wv][lane][2] = acc[2];
    Ared[wv][lane][3] = acc[3];
  }
  __syncthreads();
  {
    const int l = t & 63, j = t >> 6;
    const float s = (Ared[0][l][j] + Ared[1][l][j]) +
                    (Ared[2][l][j] + Ared[3][l][j]);
    Wtw[(l >> 4) * 4 + j][l & 15] = s;   // WtW[i][jcol], D layout per m89
  }
  __syncthreads();

  // ---- G + Neumann setup ----
  const float sg = 1.f / (1.f + expf(-gate[0]));
  {
    const int r = t >> 4, c = t & 15;
    const float gv = (r < 8) ? sg * Wtw[r + 8][c] : -sg * Wtw[r - 8][c];
    Gs[r][c] = gv;
    Ya[r][c] = ((r == c) ? 1.f : 0.f) + 0.5f * gv;   // B = I + 0.5G
  }
  __syncthreads();
#pragma unroll
  for (int m = 0; m < NEUMANN_ITERS; ++m) {   // ends in Ya (last m odd)
    const int r = t >> 4, c = t & 15;
    const float (*Yp)[17] = (m & 1) ? Yb : Ya;
    float (*Yn)[17] = (m & 1) ? Ya : Yb;
    float acc = ((r == c) ? 1.f : 0.f) + 0.5f * Gs[r][c];
#pragma unroll
    for (int j = 0; j < 16; ++j)
      acc = fmaf(0.5f * Gs[r][j], Yp[j][c], acc);
    Yn[r][c] = acc;
    __syncthreads();
  }

  // ---- phase 1: a = x.W via MFMA; wave wv covers K-slice [wv*512,+512) ----
  const int row0 = blockIdx.x * 16;
  {
    f32x4 acc = {0.f, 0.f, 0.f, 0.f};
    const float* xrow = x + (size_t)(row0 + rA) * DIM;
#pragma unroll 4
    for (int step = 0; step < 32; ++step) {
      const int d0 = wv * 512 + step * 16 + g * 4;
      const float4 xv = *(const float4*)(xrow + d0);
      uint2 au = {pkh(xv.x, xv.y), pkh(xv.z, xv.w)};
      const h4 af = __builtin_bit_cast(h4, au);
      const float w0 = Wcol[8 * (d0 + 0)], w1 = Wcol[8 * (d0 + 1)];
      const float w2 = Wcol[8 * (d0 + 2)], w3 = Wcol[8 * (d0 + 3)];
      uint2 bu = {pkh(w0, w1), pkh(w2, w3)};
      const h4 bf = __builtin_bit_cast(h4, bu);
      acc = __builtin_amdgcn_mfma_f32_16x16x16f16(af, bf, acc, 0, 0, 0);
    }
    Ared[wv][lane][0] = acc[0];
    Ared[wv][lane][1] = acc[1];
    Ared[wv][lane][2] = acc[2];
    Ared[wv][lane][3] = acc[3];
  }
  __syncthreads();
  {
    const int l = t & 63, j = t >> 6;
    const float s = (Ared[0][l][j] + Ared[1][l][j]) +
                    (Ared[2][l][j] + Ared[3][l][j]);
    As[(l >> 4) * 4 + j][l & 15] = s;   // a[row][k], D layout per m89
  }
  __syncthreads();

  // ---- c fragment (lane holds c[r=rA][g*4+j]; serves as B-operand) ----
  h4 cf;
  {
    const float hs = 0.5f * sg;
    const int r = rA;
    float cj[4];
#pragma unroll
    for (int j = 0; j < 4; ++j) {
      const int k = g * 4 + j;
      float s = 0.f;
#pragma unroll
      for (int jj = 0; jj < 8; ++jj) {
        const float zA = Ya[k][jj] + ((k == jj) ? 1.f : 0.f);
        const float zB = Ya[k][8 + jj] + ((k == 8 + jj) ? 1.f : 0.f);
        s = fmaf(zA, As[r][8 + jj], s);    //  Z[k][j']   * av[j']
        s = fmaf(-zB, As[r][jj], s);       // -Z[k][8+j'] * au[j']
      }
      cj[j] = hs * s;
    }
    uint2 cu = {pkh(cj[0], cj[1]), pkh(cj[2], cj[3])};
    cf = __builtin_bit_cast(h4, cu);
  }

  // ---- phase 2: out = x + W.c^T via MFMA (swapped operands, r25) ----
  // B-frag: W[dcol0+rA][g*4..+3] = one float4 from U4/V4 (L2-hot).
  {
    const float4* WB4 = (const float4*)((g < 2) ? U : V);
    const int gsel = g & 1;
    const float4* x4row = (const float4*)(x + (size_t)(row0 + rA) * DIM);
    float4* o4row = (float4*)(out + (size_t)(row0 + rA) * DIM);
    for (int nt = wv * 32; nt < wv * 32 + 32; ++nt) {
      const int dcol0 = nt * 16;
      const float4 wf4 = WB4[(dcol0 + rA) * 2 + gsel];
      uint2 bu = {pkh(wf4.x, wf4.y), pkh(wf4.z, wf4.w)};
      const h4 bf = __builtin_bit_cast(h4, bu);    // W[dcol0+rA][g*4+j]
      f32x4 z4 = {0.f, 0.f, 0.f, 0.f};
      const f32x4 o = __builtin_amdgcn_mfma_f32_16x16x16f16(bf, cf, z4, 0, 0, 0);
      const int q4 = (dcol0 >> 2) + g;             // float4 index in row
      const float4 xv = x4row[q4];
      float4 ov;
      ov.x = xv.x + o[0];
      ov.y = xv.y + o[1];
      ov.z = xv.z + o[2];
      ov.w = xv.w + o[3];
      o4row[q4] = ov;
    }
  }
}

extern "C" void kernel_launch(void* const* d_in, const int* in_sizes, int n_in,
                              void* d_out, int out_size, void* d_ws, size_t ws_size,
                              hipStream_t stream) {
  const float* x    = (const float*)d_in[0];
  const float* U    = (const float*)d_in[1];
  const float* V    = (const float*)d_in[2];
  const float* gate = (const float*)d_in[3];
  float* out = (float*)d_out;

  rora_fused<<<NTOK / 16, 256, 0, stream>>>(x, U, V, gate, out);
}

// Round 27
// 40.624 us; speedup vs baseline: 1.0606x; 1.0606x over previous
//
#include <hip/hip_runtime.h>
#include <hip/hip_fp16.h>
#include <cstddef>

#define DIM 2048
#define NTOK 8192
#define NEUMANN_ITERS 6
#define PLANE (DIM / 2 + 1)   // +1 uint4 pad: planes 4 banks apart (r22 fix)

// Math (validated rounds 1-26):
//   omega = P Q^T, P=[U|V], Q=[sV|-sU], G = Q^T P  (16x16)
//   Y = (I - G/2)^{-1}(I + G/2)  via Neumann-Horner: Y <- B + 0.5*G*Y, B=I+G/2
//   out = x + c . W^T,  c[r][k] = 0.5*s* sum_j Z[k][j] b[r][j],  Z = I + Y,
//     b[j<8] = av[j], b[j>=8] = -au[j-8];  a = [x.U | x.V] = x.W
//   G[r][c] = r<8 ? +s*WtW[8+r][c] : -s*WtW[r-8][c]  (in-kernel gram, r24)
//
// r27 change (on r25 champion, 41.5us): MERGE gram into phase 1. Both
// loops iterate the same K-slices with the SAME B-fragment gather; fusing
// them deletes a full serialized pass (32 MFMA + 64 ds_reads + barriers
// per wave), starts the x HBM stream earlier, and the gram MFMAs ride the
// idle matrix pipe. r26 lesson: grid 512 = 2 blocks/CU is a launch-geometry
// cap — occupancy can't rise, so cut serialized work per block instead.
// Geometry: 256 thr = 4 waves, 16 rows/block, grid 512. No workspace.

typedef _Float16 h4 __attribute__((ext_vector_type(4)));
typedef float f32x4 __attribute__((ext_vector_type(4)));

__device__ __forceinline__ unsigned pkh(float lo, float hi) {
  auto p = __builtin_amdgcn_cvt_pkrtz(lo, hi);   // v_cvt_pkrtz_f16_f32
  return __builtin_bit_cast(unsigned, p);
}

// ---------------------------------------------------------------------------
// Fused MFMA kernel. uvQ[q][P].comp(m) = half2(W[2P][4q+m], W[2P+1][4q+m]).
// 256 thr = 4 waves; block owns 16 rows; grid 512. No workspace.
// ---------------------------------------------------------------------------
__global__ __launch_bounds__(256) void rora_fused(
    const float* __restrict__ x, const float* __restrict__ U,
    const float* __restrict__ V, const float* __restrict__ gate,
    float* __restrict__ out) {
  __shared__ uint4 uvQ[4][PLANE];     // 65,600 B
  __shared__ float Gs[16][17];        // 1,088 B
  __shared__ float Ya[16][17];        // 1,088 B
  __shared__ float Yb[16][17];        // 1,088 B
  __shared__ float Wtw[16][17];       // 1,088 B
  __shared__ float As[16][17];        // 1,088 B
  __shared__ float Ared[4][64][4];    // 4,096 B
  __shared__ float Agred[4][64][4];   // 4,096 B  (total ~79.2 KB, 2 blk/CU)
  const int t = threadIdx.x;
  const int lane = t & 63, wv = t >> 6;
  const int rA = lane & 15, g = lane >> 4;

  // ---- stage U,V -> LDS as f16 d-pairs (4 pairs per thread) ----
  {
    const float4* U4 = (const float4*)U;
    const float4* V4 = (const float4*)V;
#pragma unroll
    for (int rep = 0; rep < 4; ++rep) {
      const int P = rep * 256 + t;    // d-pair (2P, 2P+1); covers 0..1023
      const float4 a0 = U4[4 * P + 0], a1 = U4[4 * P + 1];
      const float4 a2 = U4[4 * P + 2], a3 = U4[4 * P + 3];
      const float4 b0 = V4[4 * P + 0], b1 = V4[4 * P + 1];
      const float4 b2 = V4[4 * P + 2], b3 = V4[4 * P + 3];
      uvQ[0][P] = make_uint4(pkh(a0.x, a2.x), pkh(a0.y, a2.y),
                             pkh(a0.z, a2.z), pkh(a0.w, a2.w));
      uvQ[1][P] = make_uint4(pkh(a1.x, a3.x), pkh(a1.y, a3.y),
                             pkh(a1.z, a3.z), pkh(a1.w, a3.w));
      uvQ[2][P] = make_uint4(pkh(b0.x, b2.x), pkh(b0.y, b2.y),
                             pkh(b0.z, b2.z), pkh(b0.w, b2.w));
      uvQ[3][P] = make_uint4(pkh(b1.x, b3.x), pkh(b1.y, b3.y),
                             pkh(b1.z, b3.z), pkh(b1.w, b3.w));
    }
  }
  __syncthreads();   // staging visible before MFMA reads

  // ---- MERGED phase 1 + gram: wave wv covers K-slice [wv*512,+512) ----
  // a = x.W (af x bf) and WtW = W^T W (bf x bf) share the B gather.
  const int row0 = blockIdx.x * 16;
  {
    f32x4 acca = {0.f, 0.f, 0.f, 0.f};
    f32x4 accg = {0.f, 0.f, 0.f, 0.f};
    const float* xrow = x + (size_t)(row0 + rA) * DIM;
    const int q1 = rA >> 2, c1 = rA & 3;   // B column k = rA
    const unsigned* uvW = (const unsigned*)&uvQ[q1][0];
#pragma unroll 4
    for (int step = 0; step < 32; ++step) {
      const int d0 = wv * 512 + step * 16 + g * 4;
      const float4 xv = *(const float4*)(xrow + d0);
      uint2 au = {pkh(xv.x, xv.y), pkh(xv.z, xv.w)};
      const h4 af = __builtin_bit_cast(h4, au);
      const int P0 = d0 >> 1;
      uint2 bu = {uvW[P0 * 4 + c1], uvW[(P0 + 1) * 4 + c1]};
      const h4 bf = __builtin_bit_cast(h4, bu);
      acca = __builtin_amdgcn_mfma_f32_16x16x16f16(af, bf, acca, 0, 0, 0);
      accg = __builtin_amdgcn_mfma_f32_16x16x16f16(bf, bf, accg, 0, 0, 0);
    }
    Ared[wv][lane][0] = acca[0];
    Ared[wv][lane][1] = acca[1];
    Ared[wv][lane][2] = acca[2];
    Ared[wv][lane][3] = acca[3];
    Agred[wv][lane][0] = accg[0];
    Agred[wv][lane][1] = accg[1];
    Agred[wv][lane][2] = accg[2];
    Agred[wv][lane][3] = accg[3];
  }
  __syncthreads();
  {
    const int l = t & 63, j = t >> 6;
    const float sa = (Ared[0][l][j] + Ared[1][l][j]) +
                     (Ared[2][l][j] + Ared[3][l][j]);
    const float sgm = (Agred[0][l][j] + Agred[1][l][j]) +
                      (Agred[2][l][j] + Agred[3][l][j]);
    const int dr = (l >> 4) * 4 + j, dc = l & 15;   // D layout per m89
    As[dr][dc] = sa;     // a[row][k]
    Wtw[dr][dc] = sgm;   // WtW[i][jcol]
  }
  __syncthreads();

  // ---- G + Neumann setup ----
  const float sg = 1.f / (1.f + expf(-gate[0]));
  {
    const int r = t >> 4, c = t & 15;
    const float gv = (r < 8) ? sg * Wtw[r + 8][c] : -sg * Wtw[r - 8][c];
    Gs[r][c] = gv;
    Ya[r][c] = ((r == c) ? 1.f : 0.f) + 0.5f * gv;   // B = I + 0.5G
  }
  __syncthreads();
#pragma unroll
  for (int m = 0; m < NEUMANN_ITERS; ++m) {   // ends in Ya (last m odd)
    const int r = t >> 4, c = t & 15;
    const float (*Yp)[17] = (m & 1) ? Yb : Ya;
    float (*Yn)[17] = (m & 1) ? Ya : Yb;
    float acc = ((r == c) ? 1.f : 0.f) + 0.5f * Gs[r][c];
#pragma unroll
    for (int j = 0; j < 16; ++j)
      acc = fmaf(0.5f * Gs[r][j], Yp[j][c], acc);
    Yn[r][c] = acc;
    __syncthreads();
  }

  // ---- c fragment (lane holds c[r=rA][g*4+j]; serves as B-operand) ----
  h4 cf;
  {
    const float hs = 0.5f * sg;
    const int r = rA;
    float cj[4];
#pragma unroll
    for (int j = 0; j < 4; ++j) {
      const int k = g * 4 + j;
      float s = 0.f;
#pragma unroll
      for (int jj = 0; jj < 8; ++jj) {
        const float zA = Ya[k][jj] + ((k == jj) ? 1.f : 0.f);
        const float zB = Ya[k][8 + jj] + ((k == 8 + jj) ? 1.f : 0.f);
        s = fmaf(zA, As[r][8 + jj], s);    //  Z[k][j']   * av[j']
        s = fmaf(-zB, As[r][jj], s);       // -Z[k][8+j'] * au[j']
      }
      cj[j] = hs * s;
    }
    uint2 cu = {pkh(cj[0], cj[1]), pkh(cj[2], cj[3])};
    cf = __builtin_bit_cast(h4, cu);
  }

  // ---- phase 2: out = x + W.c^T via MFMA (swapped operands, r25) ----
  // D[d][r]: lane holds corr[row0+rA][dcol0+g*4+j] = one float4.
  {
    const int par = rA & 1;
    const float4* x4row = (const float4*)(x + (size_t)(row0 + rA) * DIM);
    float4* o4row = (float4*)(out + (size_t)(row0 + rA) * DIM);
    for (int nt = wv * 32; nt < wv * 32 + 32; ++nt) {
      const int dcol0 = nt * 16;
      const uint4 wq = uvQ[g][(dcol0 + rA) >> 1];  // plane q = k>>2 = g
      const unsigned w01 = par ? ((wq.x >> 16) | (wq.y & 0xffff0000u))
                               : ((wq.x & 0xffffu) | (wq.y << 16));
      const unsigned w23 = par ? ((wq.z >> 16) | (wq.w & 0xffff0000u))
                               : ((wq.z & 0xffffu) | (wq.w << 16));
      uint2 bu = {w01, w23};
      const h4 bf = __builtin_bit_cast(h4, bu);    // W[dcol0+rA][g*4+j]
      f32x4 z4 = {0.f, 0.f, 0.f, 0.f};
      const f32x4 o = __builtin_amdgcn_mfma_f32_16x16x16f16(bf, cf, z4, 0, 0, 0);
      const int q4 = (dcol0 >> 2) + g;             // float4 index in row
      const float4 xv = x4row[q4];
      float4 ov;
      ov.x = xv.x + o[0];
      ov.y = xv.y + o[1];
      ov.z = xv.z + o[2];
      ov.w = xv.w + o[3];
      o4row[q4] = ov;
    }
  }
}

extern "C" void kernel_launch(void* const* d_in, const int* in_sizes, int n_in,
                              void* d_out, int out_size, void* d_ws, size_t ws_size,
                              hipStream_t stream) {
  const float* x    = (const float*)d_in[0];
  const float* U    = (const float*)d_in[1];
  const float* V    = (const float*)d_in[2];
  const float* gate = (const float*)d_in[3];
  float* out = (float*)d_out;

  rora_fused<<<NTOK / 16, 256, 0, stream>>>(x, U, V, gate, out);
}